// Round 1
// baseline (7550.422 us; speedup 1.0000x reference)
//
#include <hip/hip_runtime.h>

// FraudGraphSAGE: 2-layer GraphSAGE (mean agg) + linear classifier.
// N=200000 nodes (12ch), E=3.2M edges.
// Pipeline:
//   detect_i64   : set ws flag if edge_index arrived as int64 (vs int32)
//   edge_pass1   : agg1[dst] += x[src] (12 f32 atomics/edge), deg[dst] += 1
//   layer1_kernel: h = relu(agg1/deg @ w1l + b1 + x @ w1r)  (in-regs, wave/node)
//                  g = h @ w2l ; r = h @ w2r + b2           (shfl-broadcast)
//   edge_pass2   : agg2[dst] += g[src] (32 f32 atomics/edge)
//   final_kernel : h2 = relu(agg2/deg + r); out = h2 @ wc + bc

#define IN_CH 12
#define HID   64
#define HID2  32

__global__ void detect_i64(const int* __restrict__ ei, int* __restrict__ flag) {
  if ((blockIdx.x | threadIdx.x) == 0) {
    // int64 little-endian: high words (odd int32 indices) of small positives are 0.
    *flag = ((ei[1] | ei[3] | ei[5] | ei[7]) == 0) ? 1 : 0;
  }
}

__global__ __launch_bounds__(256) void edge_pass1(
    const int* __restrict__ ei, const float* __restrict__ x,
    float* __restrict__ agg1, float* __restrict__ deg,
    const int* __restrict__ flag, int E) {
  int e = blockIdx.x * 256 + threadIdx.x;
  if (e >= E) return;
  int f64 = *flag;
  int src, dst;
  if (f64) { src = ei[2 * e]; dst = ei[2 * (E + e)]; }
  else     { src = ei[e];     dst = ei[E + e]; }
  atomicAdd(&deg[dst], 1.0f);
  const float4* xs = (const float4*)(x + (size_t)src * IN_CH);
  float4 v0 = xs[0], v1 = xs[1], v2 = xs[2];
  float* a = agg1 + (size_t)dst * IN_CH;
  atomicAdd(a + 0, v0.x);  atomicAdd(a + 1, v0.y);
  atomicAdd(a + 2, v0.z);  atomicAdd(a + 3, v0.w);
  atomicAdd(a + 4, v1.x);  atomicAdd(a + 5, v1.y);
  atomicAdd(a + 6, v1.z);  atomicAdd(a + 7, v1.w);
  atomicAdd(a + 8, v2.x);  atomicAdd(a + 9, v2.y);
  atomicAdd(a + 10, v2.z); atomicAdd(a + 11, v2.w);
}

__global__ __launch_bounds__(256) void layer1_kernel(
    const float* __restrict__ x, const float* __restrict__ agg1,
    const float* __restrict__ deg,
    const float* __restrict__ w1l, const float* __restrict__ b1,
    const float* __restrict__ w1r, const float* __restrict__ w2l,
    const float* __restrict__ b2, const float* __restrict__ w2r,
    float* __restrict__ g, float* __restrict__ r, int N) {
  __shared__ float s_w1l[IN_CH * HID], s_w1r[IN_CH * HID];
  __shared__ float s_w2l[HID * HID2], s_w2r[HID * HID2];
  __shared__ float s_b1[HID], s_b2[HID2];
  int t = threadIdx.x;
  for (int i = t; i < IN_CH * HID; i += 256) { s_w1l[i] = w1l[i]; s_w1r[i] = w1r[i]; }
  for (int i = t; i < HID * HID2; i += 256)  { s_w2l[i] = w2l[i]; s_w2r[i] = w2r[i]; }
  if (t < HID) s_b1[t] = b1[t];
  if (t >= HID && t < HID + HID2) s_b2[t - HID] = b2[t - HID];
  __syncthreads();

  int wave = t >> 6, lane = t & 63;
  for (int node = blockIdx.x * 4 + wave; node < N; node += gridDim.x * 4) {
    float inv = 1.0f / fmaxf(deg[node], 1.0f);
    const float* xr = x + (size_t)node * IN_CH;
    const float* ar = agg1 + (size_t)node * IN_CH;
    float acc = s_b1[lane];
#pragma unroll
    for (int k = 0; k < IN_CH; ++k) {
      acc = fmaf(ar[k] * inv, s_w1l[k * HID + lane], acc);
      acc = fmaf(xr[k],       s_w1r[k * HID + lane], acc);
    }
    float h = fmaxf(acc, 0.0f);

    // g = h @ w2l (lanes 0..31), r = h @ w2r + b2 (lanes 32..63), via shfl bcast
    int o = lane & 31;
    bool isg = lane < 32;
    const float* W = isg ? s_w2l : s_w2r;
    float a2 = isg ? 0.0f : s_b2[o];
#pragma unroll
    for (int k = 0; k < HID; ++k) {
      float hk = __shfl(h, k, 64);
      a2 = fmaf(hk, W[k * HID2 + o], a2);
    }
    if (isg) g[(size_t)node * HID2 + o] = a2;
    else     r[(size_t)node * HID2 + o] = a2;
  }
}

__global__ __launch_bounds__(256) void edge_pass2(
    const int* __restrict__ ei, const float* __restrict__ g,
    float* __restrict__ agg2, const int* __restrict__ flag, int E) {
  int e = blockIdx.x * 256 + threadIdx.x;
  if (e >= E) return;
  int f64 = *flag;
  int src, dst;
  if (f64) { src = ei[2 * e]; dst = ei[2 * (E + e)]; }
  else     { src = ei[e];     dst = ei[E + e]; }
  const float4* gs = (const float4*)(g + (size_t)src * HID2);
  float* a = agg2 + (size_t)dst * HID2;
#pragma unroll
  for (int q = 0; q < 8; ++q) {
    float4 v = gs[q];
    atomicAdd(a + q * 4 + 0, v.x);
    atomicAdd(a + q * 4 + 1, v.y);
    atomicAdd(a + q * 4 + 2, v.z);
    atomicAdd(a + q * 4 + 3, v.w);
  }
}

__global__ __launch_bounds__(256) void final_kernel(
    const float* __restrict__ agg2, const float* __restrict__ r,
    const float* __restrict__ deg, const float* __restrict__ wc,
    const float* __restrict__ bc, float* __restrict__ out, int N) {
  int t = blockIdx.x * 256 + threadIdx.x;
  int node = t >> 5;
  int lane = t & 31;
  if (node >= N) return;
  float dg = fmaxf(deg[node], 1.0f);
  size_t idx = (size_t)node * HID2 + lane;
  float v = fmaxf(agg2[idx] / dg + r[idx], 0.0f);
  float p0 = v * wc[lane * 2 + 0];
  float p1 = v * wc[lane * 2 + 1];
#pragma unroll
  for (int off = 16; off > 0; off >>= 1) {
    p0 += __shfl_down(p0, off, 32);
    p1 += __shfl_down(p1, off, 32);
  }
  if (lane == 0) {
    out[(size_t)node * 2 + 0] = p0 + bc[0];
    out[(size_t)node * 2 + 1] = p1 + bc[1];
  }
}

extern "C" void kernel_launch(void* const* d_in, const int* in_sizes, int n_in,
                              void* d_out, int out_size, void* d_ws, size_t ws_size,
                              hipStream_t stream) {
  const float* x   = (const float*)d_in[0];
  const int*   ei  = (const int*)d_in[1];
  const float* w1l = (const float*)d_in[2];
  const float* b1  = (const float*)d_in[3];
  const float* w1r = (const float*)d_in[4];
  const float* w2l = (const float*)d_in[5];
  const float* b2  = (const float*)d_in[6];
  const float* w2r = (const float*)d_in[7];
  const float* wc  = (const float*)d_in[8];
  const float* bc  = (const float*)d_in[9];
  float* out = (float*)d_out;

  int N = in_sizes[0] / IN_CH;
  int E = in_sizes[1] / 2;

  // Workspace layout (floats): deg[N] | agg1[N*12] | g[N*32] | r[N*32] | agg2[N*32] | flag
  float* ws   = (float*)d_ws;
  float* deg  = ws;
  float* agg1 = deg + N;
  float* g    = agg1 + (size_t)N * IN_CH;
  float* r    = g + (size_t)N * HID2;
  float* agg2 = r + (size_t)N * HID2;
  int*   flag = (int*)(agg2 + (size_t)N * HID2);

  // zero accumulators (deg+agg1 are contiguous)
  hipMemsetAsync(deg, 0, sizeof(float) * (size_t)N * (1 + IN_CH), stream);
  hipMemsetAsync(agg2, 0, sizeof(float) * (size_t)N * HID2, stream);

  detect_i64<<<1, 64, 0, stream>>>(ei, flag);

  int eblocks = (E + 255) / 256;
  edge_pass1<<<eblocks, 256, 0, stream>>>(ei, x, agg1, deg, flag, E);

  int l1blocks = (N + 31) / 32;  // 4 waves/block, ~8 nodes per wave
  layer1_kernel<<<l1blocks, 256, 0, stream>>>(x, agg1, deg, w1l, b1, w1r,
                                              w2l, b2, w2r, g, r, N);

  edge_pass2<<<eblocks, 256, 0, stream>>>(ei, g, agg2, flag, E);

  int fthreads = N * 32;
  final_kernel<<<(fthreads + 255) / 256, 256, 0, stream>>>(agg2, r, deg, wc, bc, out, N);
}

// Round 2
// 829.693 us; speedup vs baseline: 9.1003x; 9.1003x over previous
//
#include <hip/hip_runtime.h>

// FraudGraphSAGE: 2-layer GraphSAGE (mean agg) + linear classifier.
// N=200000 nodes (12ch), E=3.2M edges.
//
// R2 structure: replace f32-atomic scatter aggregation (atomic-bound, 20G/s)
// with CSR build (6.4M int atomics) + atomic-free coalesced gather-sums.
//   detect_i64    : flag if edge_index arrived as int64
//   count_deg     : deg[dst]++ (int atomics)
//   scan1/2/3     : exclusive scan of deg -> off[], cur[]
//   scatter_edges : pos = cur[dst]++; csr[pos] = src
//   agg1_kernel   : agg1[n] = sum_{j in N(n)} x[j]        (16 lanes/node, 12 active)
//   layer1_kernel : h = relu(agg1/deg @ w1l + b1 + x @ w1r); g = h@w2l; r = h@w2r+b2
//   agg2_final    : s = sum g[j]; v = relu(s/deg + r); out = v @ wc + bc  (32 lanes/node)

#define IN_CH 12
#define HID   64
#define HID2  32
#define SCAN_BS  256
#define SCAN_EPB 2048  // elements per scan1 block (8/thread)

__global__ void detect_i64(const int* __restrict__ ei, int* __restrict__ flag) {
  if ((blockIdx.x | threadIdx.x) == 0) {
    *flag = ((ei[1] | ei[3] | ei[5] | ei[7]) == 0) ? 1 : 0;
  }
}

__global__ __launch_bounds__(256) void count_deg(
    const int* __restrict__ ei, int* __restrict__ deg,
    const int* __restrict__ flag, int E) {
  int e = blockIdx.x * 256 + threadIdx.x;
  if (e >= E) return;
  int dst = (*flag) ? ei[2 * (E + e)] : ei[E + e];
  atomicAdd(&deg[dst], 1);
}

__global__ __launch_bounds__(SCAN_BS) void scan1(
    const int* __restrict__ deg, int* __restrict__ off,
    int* __restrict__ bsums, int N) {
  __shared__ int s[SCAN_BS];
  int t = threadIdx.x;
  int base = blockIdx.x * SCAN_EPB + t * 8;
  int v[8];
  int sum = 0;
#pragma unroll
  for (int i = 0; i < 8; ++i) { int idx = base + i; v[i] = (idx < N) ? deg[idx] : 0; sum += v[i]; }
  s[t] = sum;
  __syncthreads();
  for (int d = 1; d < SCAN_BS; d <<= 1) {
    int add = (t >= d) ? s[t - d] : 0;
    __syncthreads();
    s[t] += add;
    __syncthreads();
  }
  int run = s[t] - sum;  // exclusive prefix for this thread's first element
#pragma unroll
  for (int i = 0; i < 8; ++i) { int idx = base + i; if (idx < N) off[idx] = run; run += v[i]; }
  if (t == SCAN_BS - 1) bsums[blockIdx.x] = s[SCAN_BS - 1];
}

__global__ __launch_bounds__(SCAN_BS) void scan2(int* __restrict__ bsums, int P) {
  __shared__ int s[SCAN_BS];
  int t = threadIdx.x;
  int v[8];
  int sum = 0;
#pragma unroll
  for (int i = 0; i < 8; ++i) { int idx = t * 8 + i; v[i] = (idx < P) ? bsums[idx] : 0; sum += v[i]; }
  s[t] = sum;
  __syncthreads();
  for (int d = 1; d < SCAN_BS; d <<= 1) {
    int add = (t >= d) ? s[t - d] : 0;
    __syncthreads();
    s[t] += add;
    __syncthreads();
  }
  int run = s[t] - sum;
#pragma unroll
  for (int i = 0; i < 8; ++i) { int idx = t * 8 + i; if (idx < P) bsums[idx] = run; run += v[i]; }
}

__global__ __launch_bounds__(256) void scan3(
    int* __restrict__ off, int* __restrict__ cur,
    const int* __restrict__ bsums, int N) {
  int i = blockIdx.x * 256 + threadIdx.x;
  if (i >= N) return;
  int o = off[i] + bsums[i / SCAN_EPB];
  off[i] = o;
  cur[i] = o;
}

__global__ __launch_bounds__(256) void scatter_edges(
    const int* __restrict__ ei, int* __restrict__ cur,
    int* __restrict__ csr, const int* __restrict__ flag, int E) {
  int e = blockIdx.x * 256 + threadIdx.x;
  if (e >= E) return;
  int f64 = *flag;
  int src, dst;
  if (f64) { src = ei[2 * e]; dst = ei[2 * (E + e)]; }
  else     { src = ei[e];     dst = ei[E + e]; }
  int pos = atomicAdd(&cur[dst], 1);
  csr[pos] = src;
}

__global__ __launch_bounds__(256) void agg1_kernel(
    const int* __restrict__ off, const int* __restrict__ deg,
    const int* __restrict__ csr, const float* __restrict__ x,
    float* __restrict__ agg1, int N) {
  int tid = blockIdx.x * 256 + threadIdx.x;
  int node = tid >> 4;
  int lane = tid & 15;
  if (node >= N || lane >= IN_CH) return;
  int start = off[node], d = deg[node];
  float acc = 0.f;
  int j = 0;
  for (; j + 1 < d; j += 2) {
    int s0 = csr[start + j], s1 = csr[start + j + 1];
    acc += x[(size_t)s0 * IN_CH + lane];
    acc += x[(size_t)s1 * IN_CH + lane];
  }
  if (j < d) acc += x[(size_t)csr[start + j] * IN_CH + lane];
  agg1[(size_t)node * IN_CH + lane] = acc;
}

__global__ __launch_bounds__(256) void layer1_kernel(
    const float* __restrict__ x, const float* __restrict__ agg1,
    const int* __restrict__ deg,
    const float* __restrict__ w1l, const float* __restrict__ b1,
    const float* __restrict__ w1r, const float* __restrict__ w2l,
    const float* __restrict__ b2, const float* __restrict__ w2r,
    float* __restrict__ g, float* __restrict__ r, int N) {
  __shared__ float s_w1l[IN_CH * HID], s_w1r[IN_CH * HID];
  __shared__ float s_w2l[HID * HID2], s_w2r[HID * HID2];
  __shared__ float s_b1[HID], s_b2[HID2];
  int t = threadIdx.x;
  for (int i = t; i < IN_CH * HID; i += 256) { s_w1l[i] = w1l[i]; s_w1r[i] = w1r[i]; }
  for (int i = t; i < HID * HID2; i += 256)  { s_w2l[i] = w2l[i]; s_w2r[i] = w2r[i]; }
  if (t < HID) s_b1[t] = b1[t];
  if (t >= HID && t < HID + HID2) s_b2[t - HID] = b2[t - HID];
  __syncthreads();

  int wave = t >> 6, lane = t & 63;
  for (int node = blockIdx.x * 4 + wave; node < N; node += gridDim.x * 4) {
    float inv = 1.0f / fmaxf((float)deg[node], 1.0f);
    const float* xr = x + (size_t)node * IN_CH;
    const float* ar = agg1 + (size_t)node * IN_CH;
    float acc = s_b1[lane];
#pragma unroll
    for (int k = 0; k < IN_CH; ++k) {
      acc = fmaf(ar[k] * inv, s_w1l[k * HID + lane], acc);
      acc = fmaf(xr[k],       s_w1r[k * HID + lane], acc);
    }
    float h = fmaxf(acc, 0.0f);

    int o = lane & 31;
    bool isg = lane < 32;
    const float* W = isg ? s_w2l : s_w2r;
    float a2 = isg ? 0.0f : s_b2[o];
#pragma unroll
    for (int k = 0; k < HID; ++k) {
      float hk = __shfl(h, k, 64);
      a2 = fmaf(hk, W[k * HID2 + o], a2);
    }
    if (isg) g[(size_t)node * HID2 + o] = a2;
    else     r[(size_t)node * HID2 + o] = a2;
  }
}

__global__ __launch_bounds__(256) void agg2_final(
    const int* __restrict__ off, const int* __restrict__ deg,
    const int* __restrict__ csr, const float* __restrict__ g,
    const float* __restrict__ r, const float* __restrict__ wc,
    const float* __restrict__ bc, float* __restrict__ out, int N) {
  int tid = blockIdx.x * 256 + threadIdx.x;
  int node = tid >> 5;
  int lane = tid & 31;
  if (node >= N) return;
  int start = off[node], d = deg[node];
  float acc = 0.f;
  int j = 0;
  for (; j + 1 < d; j += 2) {
    int s0 = csr[start + j], s1 = csr[start + j + 1];
    acc += g[(size_t)s0 * HID2 + lane];
    acc += g[(size_t)s1 * HID2 + lane];
  }
  if (j < d) acc += g[(size_t)csr[start + j] * HID2 + lane];
  float dg = fmaxf((float)d, 1.0f);
  float v = fmaxf(acc / dg + r[(size_t)node * HID2 + lane], 0.0f);
  float p0 = v * wc[lane * 2 + 0];
  float p1 = v * wc[lane * 2 + 1];
#pragma unroll
  for (int o2 = 16; o2 > 0; o2 >>= 1) {
    p0 += __shfl_down(p0, o2, 32);
    p1 += __shfl_down(p1, o2, 32);
  }
  if (lane == 0) {
    out[(size_t)node * 2 + 0] = p0 + bc[0];
    out[(size_t)node * 2 + 1] = p1 + bc[1];
  }
}

extern "C" void kernel_launch(void* const* d_in, const int* in_sizes, int n_in,
                              void* d_out, int out_size, void* d_ws, size_t ws_size,
                              hipStream_t stream) {
  const float* x   = (const float*)d_in[0];
  const int*   ei  = (const int*)d_in[1];
  const float* w1l = (const float*)d_in[2];
  const float* b1  = (const float*)d_in[3];
  const float* w1r = (const float*)d_in[4];
  const float* w2l = (const float*)d_in[5];
  const float* b2  = (const float*)d_in[6];
  const float* w2r = (const float*)d_in[7];
  const float* wc  = (const float*)d_in[8];
  const float* bc  = (const float*)d_in[9];
  float* out = (float*)d_out;

  int N = in_sizes[0] / IN_CH;
  int E = in_sizes[1] / 2;

  // Workspace: deg[N] off[N] cur[N] bsums[2048] flag[1] csr[E] (ints),
  //            agg1[N*12] g[N*32] r[N*32] (floats)  ~= 76 MB
  int* deg   = (int*)d_ws;
  int* off   = deg + N;
  int* cur   = off + N;
  int* bsums = cur + N;
  int* flag  = bsums + 2048;
  int* csr   = flag + 1;
  float* agg1 = (float*)(csr + E);
  float* g    = agg1 + (size_t)N * IN_CH;
  float* r    = g + (size_t)N * HID2;

  hipMemsetAsync(deg, 0, sizeof(int) * (size_t)N, stream);
  detect_i64<<<1, 64, 0, stream>>>(ei, flag);

  int eblocks = (E + 255) / 256;
  count_deg<<<eblocks, 256, 0, stream>>>(ei, deg, flag, E);

  int P = (N + SCAN_EPB - 1) / SCAN_EPB;  // 98 for N=200000 (scan2 handles <=2048)
  scan1<<<P, SCAN_BS, 0, stream>>>(deg, off, bsums, N);
  scan2<<<1, SCAN_BS, 0, stream>>>(bsums, P);
  scan3<<<(N + 255) / 256, 256, 0, stream>>>(off, cur, bsums, N);

  scatter_edges<<<eblocks, 256, 0, stream>>>(ei, cur, csr, flag, E);

  agg1_kernel<<<((size_t)N * 16 + 255) / 256, 256, 0, stream>>>(off, deg, csr, x, agg1, N);

  int l1blocks = (N + 31) / 32;
  layer1_kernel<<<l1blocks, 256, 0, stream>>>(x, agg1, deg, w1l, b1, w1r,
                                              w2l, b2, w2r, g, r, N);

  agg2_final<<<((size_t)N * 32 + 255) / 256, 256, 0, stream>>>(off, deg, csr, g, r, wc, bc, out, N);
}

// Round 3
// 582.251 us; speedup vs baseline: 12.9676x; 1.4250x over previous
//
#include <hip/hip_runtime.h>
#include <hip/hip_bf16.h>

// FraudGraphSAGE: 2-layer GraphSAGE (mean agg) + linear classifier.
// N=200000 nodes (12ch), E=3.2M edges.
//
// R3: (a) CSR slot position captured FREE in the counting pass (epos = old
// value of the counting atomic) -> scatter_edges has zero atomics;
// (b) bf16 gather payloads: x padded to 32B rows, g rows 64B (= 1 cache line).
//   detect_i64 : flag if edge_index arrived as int64
//   count_pos  : epos[e] = deg[dst]++ (int atomic, old value kept)
//   scan1/2/3  : exclusive scan of deg -> off[]
//   scatter    : csr[off[dst]+epos[e]] = src   (atomic-free)
//   xcast      : xh[n] = bf16(x[n]) padded to 16ch
//   agg1_kernel: agg1[n] = sum x_bf16[j]   (8 lanes/node, f32 accum)
//   layer1     : h = relu(agg1/deg @ w1l + b1 + x @ w1r); g=h@w2l, r=h@w2r+b2 (bf16 out)
//   agg2_final : v = relu(sum g[j]/deg + r); out = v @ wc + bc

#define IN_CH 12
#define XPAD  16
#define HID   64
#define HID2  32
#define SCAN_BS  256
#define SCAN_EPB 2048

__global__ void detect_i64(const int* __restrict__ ei, int* __restrict__ flag) {
  if ((blockIdx.x | threadIdx.x) == 0) {
    *flag = ((ei[1] | ei[3] | ei[5] | ei[7]) == 0) ? 1 : 0;
  }
}

__global__ __launch_bounds__(256) void count_pos(
    const int* __restrict__ ei, int* __restrict__ deg,
    unsigned short* __restrict__ epos, const int* __restrict__ flag, int E) {
  int e = blockIdx.x * 256 + threadIdx.x;
  if (e >= E) return;
  int dst = (*flag) ? ei[2 * (E + e)] : ei[E + e];
  epos[e] = (unsigned short)atomicAdd(&deg[dst], 1);
}

__global__ __launch_bounds__(SCAN_BS) void scan1(
    const int* __restrict__ deg, int* __restrict__ off,
    int* __restrict__ bsums, int N) {
  __shared__ int s[SCAN_BS];
  int t = threadIdx.x;
  int base = blockIdx.x * SCAN_EPB + t * 8;
  int v[8];
  int sum = 0;
#pragma unroll
  for (int i = 0; i < 8; ++i) { int idx = base + i; v[i] = (idx < N) ? deg[idx] : 0; sum += v[i]; }
  s[t] = sum;
  __syncthreads();
  for (int d = 1; d < SCAN_BS; d <<= 1) {
    int add = (t >= d) ? s[t - d] : 0;
    __syncthreads();
    s[t] += add;
    __syncthreads();
  }
  int run = s[t] - sum;
#pragma unroll
  for (int i = 0; i < 8; ++i) { int idx = base + i; if (idx < N) off[idx] = run; run += v[i]; }
  if (t == SCAN_BS - 1) bsums[blockIdx.x] = s[SCAN_BS - 1];
}

__global__ __launch_bounds__(SCAN_BS) void scan2(int* __restrict__ bsums, int P) {
  __shared__ int s[SCAN_BS];
  int t = threadIdx.x;
  int v[8];
  int sum = 0;
#pragma unroll
  for (int i = 0; i < 8; ++i) { int idx = t * 8 + i; v[i] = (idx < P) ? bsums[idx] : 0; sum += v[i]; }
  s[t] = sum;
  __syncthreads();
  for (int d = 1; d < SCAN_BS; d <<= 1) {
    int add = (t >= d) ? s[t - d] : 0;
    __syncthreads();
    s[t] += add;
    __syncthreads();
  }
  int run = s[t] - sum;
#pragma unroll
  for (int i = 0; i < 8; ++i) { int idx = t * 8 + i; if (idx < P) bsums[idx] = run; run += v[i]; }
}

__global__ __launch_bounds__(256) void scan3(
    int* __restrict__ off, const int* __restrict__ bsums, int N) {
  int i = blockIdx.x * 256 + threadIdx.x;
  if (i >= N) return;
  off[i] = off[i] + bsums[i / SCAN_EPB];
}

__global__ __launch_bounds__(256) void scatter_edges(
    const int* __restrict__ ei, const int* __restrict__ off,
    const unsigned short* __restrict__ epos, int* __restrict__ csr,
    const int* __restrict__ flag, int E) {
  int e = blockIdx.x * 256 + threadIdx.x;
  if (e >= E) return;
  int f64 = *flag;
  int src, dst;
  if (f64) { src = ei[2 * e]; dst = ei[2 * (E + e)]; }
  else     { src = ei[e];     dst = ei[E + e]; }
  csr[off[dst] + (int)epos[e]] = src;
}

__global__ __launch_bounds__(256) void xcast(
    const float* __restrict__ x, unsigned short* __restrict__ xh, int N) {
  int i = blockIdx.x * 256 + threadIdx.x;
  if (i >= N * XPAD) return;
  int n = i >> 4, c = i & 15;
  float v = (c < IN_CH) ? x[(size_t)n * IN_CH + c] : 0.f;
  union { float f; unsigned int u; } cv;
  cv.f = v;
  unsigned int b = cv.u;
  unsigned int rounded = (b + 0x7fffu + ((b >> 16) & 1u)) >> 16;  // RNE
  xh[i] = (unsigned short)rounded;
}

__global__ __launch_bounds__(256) void agg1_kernel(
    const int* __restrict__ off, const int* __restrict__ deg,
    const int* __restrict__ csr, const unsigned int* __restrict__ xh2,
    float* __restrict__ agg1, int N) {
  int tid = blockIdx.x * 256 + threadIdx.x;
  int node = tid >> 3;
  int l = tid & 7;           // lane handles channels 2l, 2l+1
  if (node >= N || l >= 6) return;  // channels 12..15 are padding
  int start = off[node], d = deg[node];
  float a0 = 0.f, a1 = 0.f;
  int j = 0;
  for (; j + 1 < d; j += 2) {
    int s0 = csr[start + j], s1 = csr[start + j + 1];
    unsigned int w0 = xh2[(size_t)s0 * 8 + l];
    unsigned int w1 = xh2[(size_t)s1 * 8 + l];
    a0 += __uint_as_float(w0 << 16) + __uint_as_float(w1 << 16);
    a1 += __uint_as_float(w0 & 0xffff0000u) + __uint_as_float(w1 & 0xffff0000u);
  }
  if (j < d) {
    unsigned int w0 = xh2[(size_t)csr[start + j] * 8 + l];
    a0 += __uint_as_float(w0 << 16);
    a1 += __uint_as_float(w0 & 0xffff0000u);
  }
  int c = 2 * l;
  agg1[(size_t)node * IN_CH + c]     = a0;
  agg1[(size_t)node * IN_CH + c + 1] = a1;
}

__device__ __forceinline__ unsigned short f2bf(float f) {
  union { float f; unsigned int u; } cv; cv.f = f;
  unsigned int b = cv.u;
  return (unsigned short)((b + 0x7fffu + ((b >> 16) & 1u)) >> 16);
}

__global__ __launch_bounds__(256) void layer1_kernel(
    const float* __restrict__ x, const float* __restrict__ agg1,
    const int* __restrict__ deg,
    const float* __restrict__ w1l, const float* __restrict__ b1,
    const float* __restrict__ w1r, const float* __restrict__ w2l,
    const float* __restrict__ b2, const float* __restrict__ w2r,
    unsigned short* __restrict__ g, unsigned short* __restrict__ r, int N) {
  __shared__ float s_w1l[IN_CH * HID], s_w1r[IN_CH * HID];
  __shared__ float s_w2l[HID * HID2], s_w2r[HID * HID2];
  __shared__ float s_b1[HID], s_b2[HID2];
  int t = threadIdx.x;
  for (int i = t; i < IN_CH * HID; i += 256) { s_w1l[i] = w1l[i]; s_w1r[i] = w1r[i]; }
  for (int i = t; i < HID * HID2; i += 256)  { s_w2l[i] = w2l[i]; s_w2r[i] = w2r[i]; }
  if (t < HID) s_b1[t] = b1[t];
  if (t >= HID && t < HID + HID2) s_b2[t - HID] = b2[t - HID];
  __syncthreads();

  int wave = t >> 6, lane = t & 63;
  for (int node = blockIdx.x * 4 + wave; node < N; node += gridDim.x * 4) {
    float inv = 1.0f / fmaxf((float)deg[node], 1.0f);
    const float* xr = x + (size_t)node * IN_CH;
    const float* ar = agg1 + (size_t)node * IN_CH;
    float acc = s_b1[lane];
#pragma unroll
    for (int k = 0; k < IN_CH; ++k) {
      acc = fmaf(ar[k] * inv, s_w1l[k * HID + lane], acc);
      acc = fmaf(xr[k],       s_w1r[k * HID + lane], acc);
    }
    float h = fmaxf(acc, 0.0f);

    int o = lane & 31;
    bool isg = lane < 32;
    const float* W = isg ? s_w2l : s_w2r;
    float a2 = isg ? 0.0f : s_b2[o];
#pragma unroll
    for (int k = 0; k < HID; ++k) {
      float hk = __shfl(h, k, 64);
      a2 = fmaf(hk, W[k * HID2 + o], a2);
    }
    if (isg) g[(size_t)node * HID2 + o] = f2bf(a2);
    else     r[(size_t)node * HID2 + o] = f2bf(a2);
  }
}

__global__ __launch_bounds__(256) void agg2_final(
    const int* __restrict__ off, const int* __restrict__ deg,
    const int* __restrict__ csr, const unsigned short* __restrict__ g,
    const unsigned short* __restrict__ r, const float* __restrict__ wc,
    const float* __restrict__ bc, float* __restrict__ out, int N) {
  int tid = blockIdx.x * 256 + threadIdx.x;
  int node = tid >> 5;
  int lane = tid & 31;
  if (node >= N) return;
  int start = off[node], d = deg[node];
  float acc = 0.f;
  int j = 0;
  for (; j + 1 < d; j += 2) {
    int s0 = csr[start + j], s1 = csr[start + j + 1];
    unsigned int w0 = g[(size_t)s0 * HID2 + lane];
    unsigned int w1 = g[(size_t)s1 * HID2 + lane];
    acc += __uint_as_float(w0 << 16) + __uint_as_float(w1 << 16);
  }
  if (j < d) {
    unsigned int w0 = g[(size_t)csr[start + j] * HID2 + lane];
    acc += __uint_as_float(w0 << 16);
  }
  float dg = fmaxf((float)d, 1.0f);
  unsigned int rw = r[(size_t)node * HID2 + lane];
  float v = fmaxf(acc / dg + __uint_as_float(rw << 16), 0.0f);
  float p0 = v * wc[lane * 2 + 0];
  float p1 = v * wc[lane * 2 + 1];
#pragma unroll
  for (int o2 = 16; o2 > 0; o2 >>= 1) {
    p0 += __shfl_down(p0, o2, 32);
    p1 += __shfl_down(p1, o2, 32);
  }
  if (lane == 0) {
    out[(size_t)node * 2 + 0] = p0 + bc[0];
    out[(size_t)node * 2 + 1] = p1 + bc[1];
  }
}

extern "C" void kernel_launch(void* const* d_in, const int* in_sizes, int n_in,
                              void* d_out, int out_size, void* d_ws, size_t ws_size,
                              hipStream_t stream) {
  const float* x   = (const float*)d_in[0];
  const int*   ei  = (const int*)d_in[1];
  const float* w1l = (const float*)d_in[2];
  const float* b1  = (const float*)d_in[3];
  const float* w1r = (const float*)d_in[4];
  const float* w2l = (const float*)d_in[5];
  const float* b2  = (const float*)d_in[6];
  const float* w2r = (const float*)d_in[7];
  const float* wc  = (const float*)d_in[8];
  const float* bc  = (const float*)d_in[9];
  float* out = (float*)d_out;

  int N = in_sizes[0] / IN_CH;
  int E = in_sizes[1] / 2;

  // Workspace: ints deg[N] off[N] bsums[2048] flag[1] csr[E];
  // f32 agg1[N*12]; u16 epos[E] xh[N*16] g[N*32] r[N*32]   (~62 MB)
  int* deg   = (int*)d_ws;
  int* off   = deg + N;
  int* bsums = off + N;
  int* flag  = bsums + 2048;
  int* csr   = flag + 1;
  float* agg1 = (float*)(csr + E);
  unsigned short* epos = (unsigned short*)(agg1 + (size_t)N * IN_CH);
  unsigned short* xh   = epos + E;          // E even -> 4B aligned
  unsigned short* g    = xh + (size_t)N * XPAD;
  unsigned short* r    = g + (size_t)N * HID2;

  hipMemsetAsync(deg, 0, sizeof(int) * (size_t)N, stream);
  detect_i64<<<1, 64, 0, stream>>>(ei, flag);

  int eblocks = (E + 255) / 256;
  count_pos<<<eblocks, 256, 0, stream>>>(ei, deg, epos, flag, E);

  xcast<<<((size_t)N * XPAD + 255) / 256, 256, 0, stream>>>(x, xh, N);

  int P = (N + SCAN_EPB - 1) / SCAN_EPB;
  scan1<<<P, SCAN_BS, 0, stream>>>(deg, off, bsums, N);
  scan2<<<1, SCAN_BS, 0, stream>>>(bsums, P);
  scan3<<<(N + 255) / 256, 256, 0, stream>>>(off, bsums, N);

  scatter_edges<<<eblocks, 256, 0, stream>>>(ei, off, epos, csr, flag, E);

  agg1_kernel<<<((size_t)N * 8 + 255) / 256, 256, 0, stream>>>(
      off, deg, csr, (const unsigned int*)xh, agg1, N);

  int l1blocks = (N + 31) / 32;
  layer1_kernel<<<l1blocks, 256, 0, stream>>>(x, agg1, deg, w1l, b1, w1r,
                                              w2l, b2, w2r, g, r, N);

  agg2_final<<<((size_t)N * 32 + 255) / 256, 256, 0, stream>>>(
      off, deg, csr, g, r, wc, bc, out, N);
}